// Round 2
// 334.634 us; speedup vs baseline: 1.0626x; 1.0626x over previous
//
#include <hip/hip_runtime.h>
#include <hip/hip_fp16.h>

// Problem constants
#define B_   128
#define N_   68
#define C_   3
#define P_   32
#define K_   16
#define FD_  64
#define GH_  128
#define EG_  544          // 8*N
#define T_   8704         // B*N
#define FLAT_ 4096        // K*16*16
#define FCH_ 16           // f-chunks in lin1 (K-split of 256)

typedef __attribute__((ext_vector_type(8))) _Float16 half8;
typedef __attribute__((ext_vector_type(2))) _Float16 half2v;
typedef __attribute__((ext_vector_type(4))) float   floatx4;

__device__ __forceinline__ half2v h2bits(float f) {
  return __builtin_bit_cast(half2v, f);
}
__device__ __forceinline__ float fdot2(half2v a, half2v b, float c) {
  return __builtin_amdgcn_fdot2(a, b, c, false);
}

// ---------------------------------------------------------------------------
// K1: per-node conv3x3(SAME) + bias + relu + maxpool2x2 -> pooled[T][4096] fp16
// One block per node. v_dot2_f32_f16 path: fp16 multiplies, fp32 accumulate.
// 27-tap reduction per output = 13 dot2 (9 c01-pairs + 4 c2-pairs) + 1 fp32 fma.
// Weights pre-packed to half2 pairs in LDS (16 dwords per k -> 4 b128 reads).
// ---------------------------------------------------------------------------
__global__ __launch_bounds__(256) void conv_pool_kernel(
    const float* __restrict__ x, const float* __restrict__ conv_w,
    const float* __restrict__ conv_b, _Float16* __restrict__ pooled) {
  const int t = blockIdx.x;
  const int n = t % N_;
  const int tid = threadIdx.x;

  __shared__ float xs[3 * 34 * 34];   // zero-padded [c][34][34], fp32
  __shared__ float wS[K_ * 16];       // [k][16] packed: 9 c01-half2, 4 c2-half2,
                                      //   w2_single(f32), bias(f32), pad

  // stage + pack weights: one dword per thread (K_*16 == 256)
  {
    const float* wp = conv_w + (size_t)n * (K_ * 27);
    const float* bp = conv_b + (size_t)n * K_;
    int k = tid >> 4, j = tid & 15;
    const float* w = wp + k * 27;
    float v;
    if (j < 9) {                       // pair (c0,c1) at tap j = dy*3+dx
      half2v h = {(_Float16)w[j], (_Float16)w[9 + j]};
      v = __builtin_bit_cast(float, h);
    } else if (j < 13) {               // c2 linear-tap pairs (0,1)(2,3)(4,5)(6,7)
      int o = (j - 9) * 2;
      half2v h = {(_Float16)w[18 + o], (_Float16)w[18 + o + 1]};
      v = __builtin_bit_cast(float, h);
    } else if (j == 13) {
      v = w[26];                       // c2 tap (2,2), kept fp32
    } else if (j == 14) {
      v = bp[k];                       // bias fp32
    } else {
      v = 0.0f;
    }
    wS[tid] = v;
  }

  // zero only the 1-wide border (interior fully overwritten)
  for (int i = tid; i < 396; i += 256) {
    int c = i / 132, j = i - c * 132;
    int off;
    if (j < 34)       off = j;                       // top row
    else if (j < 68)  off = 33 * 34 + (j - 34);      // bottom row
    else if (j < 100) off = (j - 68 + 1) * 34;       // left col
    else              off = (j - 100 + 1) * 34 + 33; // right col
    xs[c * 1156 + off] = 0.0f;
  }
  const float4* xg = (const float4*)(x + (size_t)t * (C_ * P_ * P_));
  #pragma unroll
  for (int j = 0; j < 3; j++) {
    int i4 = tid + j * 256;          // 768 float4 total
    float4 v = xg[i4];
    int f0 = i4 * 4;
    int c = f0 >> 10, rem = f0 & 1023, y = rem >> 5, xc = rem & 31;
    float* dstp = &xs[c * 1156 + (y + 1) * 34 + xc + 1];
    dstp[0] = v.x; dstp[1] = v.y; dstp[2] = v.z; dstp[3] = v.w;
  }
  __syncthreads();

  const int py = tid >> 4, px = tid & 15;

  // --- build per-thread fp16 packs from the 4x4x3 window -------------------
  // c0/c1 channel pairs, shared by all 4 outputs
  half2v pc[4][4];
  #pragma unroll
  for (int r = 0; r < 4; r++)
    #pragma unroll
    for (int cc = 0; cc < 4; cc++) {
      float x0 = xs[0 * 1156 + (2 * py + r) * 34 + (2 * px + cc)];
      float x1 = xs[1 * 1156 + (2 * py + r) * 34 + (2 * px + cc)];
      pc[r][cc] = (half2v){(_Float16)x0, (_Float16)x1};
    }
  // c2 window fp32
  float x2[4][4];
  #pragma unroll
  for (int r = 0; r < 4; r++)
    #pragma unroll
    for (int cc = 0; cc < 4; cc++)
      x2[r][cc] = xs[2 * 1156 + (2 * py + r) * 34 + (2 * px + cc)];
  // c2 linear-tap pair packs, per output quadrant (oy,ox)
  half2v p2[2][2][4];
  #pragma unroll
  for (int oy = 0; oy < 2; oy++)
    #pragma unroll
    for (int ox = 0; ox < 2; ox++)
      #pragma unroll
      for (int j = 0; j < 4; j++) {
        const int o0 = 2 * j, o1 = 2 * j + 1;
        const int dy0 = o0 / 3, dx0 = o0 % 3;
        const int dy1 = o1 / 3, dx1 = o1 % 3;
        p2[oy][ox][j] = (half2v){(_Float16)x2[oy + dy0][ox + dx0],
                                 (_Float16)x2[oy + dy1][ox + dx1]};
      }
  // c2 single tap (2,2) per output, fp32
  float x2s[2][2];
  #pragma unroll
  for (int oy = 0; oy < 2; oy++)
    #pragma unroll
    for (int ox = 0; ox < 2; ox++)
      x2s[oy][ox] = x2[oy + 2][ox + 2];

  _Float16* outp = pooled + (size_t)t * FLAT_ + py * 16 + px;

  #pragma unroll 2
  for (int k = 0; k < K_; k++) {
    const float4* wk4 = (const float4*)&wS[k * 16];
    float4 q0 = wk4[0], q1 = wk4[1], q2 = wk4[2], q3 = wk4[3];  // broadcast
    half2v w01[9];
    w01[0] = h2bits(q0.x); w01[1] = h2bits(q0.y); w01[2] = h2bits(q0.z);
    w01[3] = h2bits(q0.w); w01[4] = h2bits(q1.x); w01[5] = h2bits(q1.y);
    w01[6] = h2bits(q1.z); w01[7] = h2bits(q1.w); w01[8] = h2bits(q2.x);
    half2v w2p[4];
    w2p[0] = h2bits(q2.y); w2p[1] = h2bits(q2.z);
    w2p[2] = h2bits(q2.w); w2p[3] = h2bits(q3.x);
    const float w2s = q3.y;
    const float bk  = q3.z;

    float a[2][2];
    #pragma unroll
    for (int oy = 0; oy < 2; oy++)
      #pragma unroll
      for (int ox = 0; ox < 2; ox++) {
        float acc = bk;
        #pragma unroll
        for (int dy = 0; dy < 3; dy++)
          #pragma unroll
          for (int dx = 0; dx < 3; dx++)
            acc = fdot2(pc[oy + dy][ox + dx], w01[dy * 3 + dx], acc);
        #pragma unroll
        for (int j = 0; j < 4; j++)
          acc = fdot2(p2[oy][ox][j], w2p[j], acc);
        acc = fmaf(x2s[oy][ox], w2s, acc);
        a[oy][ox] = acc;
      }
    float m = fmaxf(fmaxf(a[0][0], a[0][1]), fmaxf(a[1][0], a[1][1]));
    m = fmaxf(m, 0.0f);
    outp[k * 256] = (_Float16)m;
  }
}

// ---------------------------------------------------------------------------
// K2: per-type linear via fp16 MFMA 16x16x32. Grid = 68 types x 16 f-chunks
// (K=256 each) = 1088 blocks, 256 threads. Wave: 32 rows x 64 outs (2x4
// frags). 4 K-steps of 64. B transposed into LDS via packed half2 writes.
// Writes DETERMINISTIC partials part[fc][t][64] fp32.
// ---------------------------------------------------------------------------
__global__ __launch_bounds__(256) void lin1_mfma_kernel(
    const _Float16* __restrict__ pooled, const float* __restrict__ lin1_w,
    float* __restrict__ part) {
  const int n   = blockIdx.x >> 4;
  const int fc  = blockIdx.x & 15;
  const int tid = threadIdx.x;
  const int wave = tid >> 6, lane = tid & 63;
  const int q = lane >> 4, lr = lane & 15;

  __shared__ __align__(16) _Float16 As[128 * 72];  // 128 rows x 64 k, pitch 72
  __shared__ __align__(16) _Float16 Bt[64 * 72];   // 64 outs x 64 k

  floatx4 acc[2][4];
  #pragma unroll
  for (int mt = 0; mt < 2; mt++)
    #pragma unroll
    for (int nt = 0; nt < 4; nt++)
      acc[mt][nt] = (floatx4){0.f, 0.f, 0.f, 0.f};

  const int f_base = fc * 256;
  for (int step = 0; step < 4; step++) {
    const int f0 = f_base + step * 64;

    // stage A: 128 rows x 64 fp16; 1024 16B-chunks, 4/thread
    #pragma unroll
    for (int j = 0; j < 4; j++) {
      int idx = tid + j * 256;
      int r = idx >> 3, ch = idx & 7;
      uint4 v = *(const uint4*)&pooled[(size_t)(r * N_ + n) * FLAT_ + f0 + ch * 8];
      *(uint4*)&As[r * 72 + ch * 8] = v;
    }
    // stage B: w slice [64 k][64 o]; cvt fp32->fp16 + transpose via half2 packs
    const float* wg = &lin1_w[(size_t)n * (FLAT_ * FD_) + (size_t)f0 * FD_];
    #pragma unroll
    for (int it = 0; it < 2; it++) {
      int p = tid + it * 256;            // 512 (k-pair, o-quad) units
      int o0 = (p & 15) * 4, k0 = (p >> 4) * 2;
      const float* wgk = wg + k0 * 64 + o0;
      float4 va = *(const float4*)wgk;
      float4 vb = *(const float4*)(wgk + 64);
      *(half2v*)&Bt[(o0 + 0) * 72 + k0] = (half2v){(_Float16)va.x, (_Float16)vb.x};
      *(half2v*)&Bt[(o0 + 1) * 72 + k0] = (half2v){(_Float16)va.y, (_Float16)vb.y};
      *(half2v*)&Bt[(o0 + 2) * 72 + k0] = (half2v){(_Float16)va.z, (_Float16)vb.z};
      *(half2v*)&Bt[(o0 + 3) * 72 + k0] = (half2v){(_Float16)va.w, (_Float16)vb.w};
    }
    __syncthreads();

    #pragma unroll
    for (int kh = 0; kh < 2; kh++) {
      half8 af[2], bf[4];
      #pragma unroll
      for (int mt = 0; mt < 2; mt++)
        af[mt] = *(const half8*)&As[(wave * 32 + mt * 16 + lr) * 72 + kh * 32 + q * 8];
      #pragma unroll
      for (int nt = 0; nt < 4; nt++)
        bf[nt] = *(const half8*)&Bt[(nt * 16 + lr) * 72 + kh * 32 + q * 8];
      #pragma unroll
      for (int mt = 0; mt < 2; mt++)
        #pragma unroll
        for (int nt = 0; nt < 4; nt++)
          acc[mt][nt] = __builtin_amdgcn_mfma_f32_16x16x32_f16(
              af[mt], bf[nt], acc[mt][nt], 0, 0, 0);
    }
    __syncthreads();
  }

  // store partials: D layout col=lane&15, row=quad*4+reg
  float* pb = part + (size_t)fc * T_ * FD_;
  #pragma unroll
  for (int mt = 0; mt < 2; mt++) {
    #pragma unroll
    for (int v = 0; v < 4; v++) {
      int r = wave * 32 + mt * 16 + q * 4 + v;
      size_t base = (size_t)(r * N_ + n) * FD_;
      #pragma unroll
      for (int nt = 0; nt < 4; nt++)
        pb[base + nt * 16 + lr] = acc[mt][nt][v];
    }
  }
}

// ---------------------------------------------------------------------------
// K3a: feats = relu(sum of 16 partials + lin1_b). Grid 544x256, float4/thread.
// ---------------------------------------------------------------------------
__global__ __launch_bounds__(256) void feats_kernel(
    const float* __restrict__ part, const float* __restrict__ lin1_b,
    float* __restrict__ feats) {
  int gid = blockIdx.x * 256 + threadIdx.x;      // T*64/4 = 139264 float4
  int t = gid >> 4, f4 = (gid & 15) * 4;
  int n = t % N_;
  float4 s = *(const float4*)&lin1_b[n * FD_ + f4];
  #pragma unroll
  for (int fc = 0; fc < FCH_; fc++) {
    float4 v = *(const float4*)&part[((size_t)fc * T_ + t) * FD_ + f4];
    s.x += v.x; s.y += v.y; s.z += v.z; s.w += v.w;
  }
  s.x = fmaxf(s.x, 0.f); s.y = fmaxf(s.y, 0.f);
  s.z = fmaxf(s.z, 0.f); s.w = fmaxf(s.w, 0.f);
  *(float4*)&feats[(size_t)t * FD_ + f4] = s;
}

// ---------------------------------------------------------------------------
// K3b: GCN aggregation, block = (graph, f-half of 32). 256 blocks x 256 thr.
// Edges + norms staged in LDS; scatter with LDS atomics (conflict-free banks).
// ---------------------------------------------------------------------------
__global__ __launch_bounds__(256) void gcn_agg_kernel(
    const float* __restrict__ feats, const int* __restrict__ edge_index,
    float* __restrict__ agg) {
  const int b  = blockIdx.x >> 1;
  const int fh = blockIdx.x & 1;        // f0 = fh*32
  const int tid = threadIdx.x;

  __shared__ float fS[N_ * 33], aS[N_ * 33];
  __shared__ int   esrcS[EG_], edstS[EG_];
  __shared__ float nrmS[EG_];
  __shared__ int   degS[N_];
  __shared__ float disS[N_];

  if (tid < N_) degS[tid] = 0;
  const int* srcp = edge_index;
  const int* dstp = edge_index + (B_ * EG_);
  const int e0 = b * EG_, nbase = b * N_;
  for (int e = tid; e < EG_; e += 256) {
    esrcS[e] = srcp[e0 + e] - nbase;
    edstS[e] = dstp[e0 + e] - nbase;
  }
  for (int idx = tid; idx < N_ * 32; idx += 256) {
    int i = idx >> 5, f = idx & 31;
    fS[i * 33 + f] = feats[(size_t)(b * N_ + i) * FD_ + fh * 32 + f];
  }
  __syncthreads();
  for (int e = tid; e < EG_; e += 256) atomicAdd(&degS[edstS[e]], 1);
  __syncthreads();
  if (tid < N_) disS[tid] = rsqrtf((float)(degS[tid] + 1));   // +1 self-loop
  __syncthreads();
  for (int e = tid; e < EG_; e += 256)
    nrmS[e] = disS[esrcS[e]] * disS[edstS[e]];
  for (int idx = tid; idx < N_ * 32; idx += 256) {
    int i = idx >> 5, f = idx & 31;
    float d = disS[i];
    aS[i * 33 + f] = d * d * fS[i * 33 + f];
  }
  __syncthreads();
  for (int idx = tid; idx < EG_ * 32; idx += 256) {
    int e = idx >> 5, f = idx & 31;
    atomicAdd(&aS[edstS[e] * 33 + f], nrmS[e] * fS[esrcS[e] * 33 + f]);
  }
  __syncthreads();
  for (int idx = tid; idx < N_ * 32; idx += 256) {
    int i = idx >> 5, f = idx & 31;
    agg[(size_t)(b * N_ + i) * FD_ + fh * 32 + f] = aS[i * 33 + f];
  }
}

// ---------------------------------------------------------------------------
// K3c: per-graph GEMM [68,64]@[64,128] + gcn_b + relu + mean-pool + MLP head.
// 128 blocks x 512 threads; w column hoisted to VGPRs (conflict-free reads).
// ---------------------------------------------------------------------------
__global__ __launch_bounds__(512) void gcn_head_kernel(
    const float* __restrict__ agg, const float* __restrict__ gcn_w,
    const float* __restrict__ gcn_b, const float* __restrict__ w1,
    const float* __restrict__ b1, const float* __restrict__ w2,
    const float* __restrict__ b2, float* __restrict__ out) {
  const int b = blockIdx.x;
  const int tid = threadIdx.x;

  __shared__ float aS[N_ * 68];      // [68][64] pitch 68
  __shared__ float wS[FD_ * GH_];    // 32 KB
  __shared__ float gP[4][GH_];
  __shared__ float z1S[64];

  for (int i4 = tid; i4 < N_ * 16; i4 += 512) {
    int i = i4 >> 4, qf = (i4 & 15) * 4;
    *(float4*)&aS[i * 68 + qf] = *(const float4*)&agg[(size_t)(b * N_ + i) * FD_ + qf];
  }
  #pragma unroll
  for (int j = 0; j < 4; j++)
    ((float4*)wS)[tid + j * 512] = ((const float4*)gcn_w)[tid + j * 512];
  __syncthreads();

  const int j = tid & 127, ig = tid >> 7;
  float wc[64];
  #pragma unroll
  for (int k = 0; k < 64; k++) wc[k] = wS[k * GH_ + j];
  const float bias = gcn_b[j];
  float gsum = 0.f;
  for (int i = ig; i < N_; i += 4) {
    float acc = bias;
    #pragma unroll
    for (int kq = 0; kq < 16; kq++) {
      float4 a = *(const float4*)&aS[i * 68 + kq * 4];   // broadcast
      acc += a.x * wc[kq * 4] + a.y * wc[kq * 4 + 1]
           + a.z * wc[kq * 4 + 2] + a.w * wc[kq * 4 + 3];
    }
    gsum += fmaxf(acc, 0.f);
  }
  gP[ig][j] = gsum;
  __syncthreads();
  if (tid < GH_)
    gP[0][tid] = (gP[0][tid] + gP[1][tid] + gP[2][tid] + gP[3][tid]) * (1.f / 68.f);
  __syncthreads();
  if (tid < 64) {
    float s = b1[tid];
    #pragma unroll 8
    for (int jj = 0; jj < GH_; jj++) s += gP[0][jj] * w1[jj * 64 + tid];
    z1S[tid] = fmaxf(s, 0.f);
  }
  __syncthreads();
  if (tid < 2) {
    float s = b2[tid];
    #pragma unroll 8
    for (int jj = 0; jj < 64; jj++) s += z1S[jj] * w2[jj * 2 + tid];
    out[b * 2 + tid] = s;
  }
}

// ---------------------------------------------------------------------------
extern "C" void kernel_launch(void* const* d_in, const int* in_sizes, int n_in,
                              void* d_out, int out_size, void* d_ws, size_t ws_size,
                              hipStream_t stream) {
  const float* x        = (const float*)d_in[0];
  const int*   edge_idx = (const int*)d_in[1];
  // d_in[2] = batch (layout known: t -> t/N), unused
  const float* conv_w   = (const float*)d_in[3];
  const float* conv_b   = (const float*)d_in[4];
  const float* lin1_w   = (const float*)d_in[5];
  const float* lin1_b   = (const float*)d_in[6];
  const float* gcn_w    = (const float*)d_in[7];
  const float* gcn_b    = (const float*)d_in[8];
  const float* mlp_w1   = (const float*)d_in[9];
  const float* mlp_b1   = (const float*)d_in[10];
  const float* mlp_w2   = (const float*)d_in[11];
  const float* mlp_b2   = (const float*)d_in[12];
  float* outp = (float*)d_out;

  char* wsb = (char*)d_ws;
  _Float16* pooled = (_Float16*)wsb;                               // 71.3 MB
  float* part  = (float*)(wsb + (size_t)T_ * FLAT_ * 2);           // 35.7 MB
  float* feats = part + (size_t)FCH_ * T_ * FD_;                   //  2.2 MB
  float* agg   = feats + (size_t)T_ * FD_;                         //  2.2 MB

  conv_pool_kernel<<<T_, 256, 0, stream>>>(x, conv_w, conv_b, pooled);
  lin1_mfma_kernel<<<N_ * FCH_, 256, 0, stream>>>(pooled, lin1_w, part);
  feats_kernel<<<544, 256, 0, stream>>>(part, lin1_b, feats);
  gcn_agg_kernel<<<B_ * 2, 256, 0, stream>>>(feats, edge_idx, agg);
  gcn_head_kernel<<<B_, 512, 0, stream>>>(agg, gcn_w, gcn_b,
                                          mlp_w1, mlp_b1, mlp_w2, mlp_b2, outp);
}

// Round 3
// 315.320 us; speedup vs baseline: 1.1277x; 1.0613x over previous
//
#include <hip/hip_runtime.h>
#include <hip/hip_fp16.h>

// Problem constants
#define B_   128
#define N_   68
#define C_   3
#define P_   32
#define K_   16
#define FD_  64
#define GH_  128
#define EG_  544          // 8*N
#define T_   8704         // B*N
#define FLAT_ 4096        // K*16*16
#define FCH_ 16           // f-chunks in lin1 (K-split of 256)

typedef __attribute__((ext_vector_type(8))) _Float16 half8;
typedef __attribute__((ext_vector_type(2))) _Float16 half2v;
typedef __attribute__((ext_vector_type(4))) float   floatx4;
typedef __attribute__((ext_vector_type(4))) unsigned int uint32x4;

#define XPITCH 1164   // fp16 channel pitch for xs (34*34=1156 + 8 pad, even, bank-spread)

// ---------------------------------------------------------------------------
// K1: per-node conv3x3(SAME)+bias+relu+maxpool2x2 -> pooled[T][4096] fp16.
// MFMA formulation: D[16ch x 16 pooled-spatial] per quad, 4 sub-tiles
// (sy,sx in {0,1}^2) = the 4 pool partners, max'd in-lane.
//   main MFMA K=32: 4 q-groups x {2 chunk-rows x 4 cols}; chunk-row cr=2q+r
//     maps to (c=cr/3, dy=cr%3)  -> covers 8 of 9 (c,dy) rows.
//   corr MFMA K=32: q0 slots 0-3 = (c2,dy2) cols, rest zero-weight.
// B-fragment (image) is SHARED between sx=0/1 (4-col window covers both tap
// alignments); only A (weights, pre-packed per sx in LDS) differs.
// xs stored fp16: all reads are dword-aligned (x-stride 2).
// ---------------------------------------------------------------------------
__global__ __launch_bounds__(256) void conv_pool_kernel(
    const float* __restrict__ x, const float* __restrict__ conv_w,
    const float* __restrict__ conv_b, _Float16* __restrict__ pooled) {
  const int t = blockIdx.x;
  const int n = t % N_;
  const int tid = threadIdx.x;

  __shared__ _Float16 xsh[3 * XPITCH];               // [c][34 rows][34 cols] fp16
  __shared__ __align__(16) _Float16 wAS[2][16][32];  // main frags per sx
  __shared__ __align__(16) _Float16 wCS[2][16][32];  // corr frags per sx
  __shared__ __align__(16) float bS[16];

  const float* wp = conv_w + (size_t)n * (K_ * 27);

  // ---- weight staging: main fragments ----
  // slot = q*8 + r*4 + col ; cr = 2q+r -> c=cr/3, dy=cr%3 ; dx = col - sx
  for (int i = tid; i < 1024; i += 256) {
    int sx = i >> 9, k = (i >> 5) & 15, slot = i & 31;
    int q = slot >> 3, r = (slot >> 2) & 1, col = slot & 3;
    int cr = q * 2 + r, c = cr / 3, dy = cr - c * 3, dx = col - sx;
    float v = (dx >= 0 && dx < 3) ? wp[k * 27 + c * 9 + dy * 3 + dx] : 0.0f;
    wAS[sx][k][slot] = (_Float16)v;
  }
  // ---- corr fragments: only q0 slots 0-3 nonzero = (c2,dy2) row ----
  for (int i = tid; i < 1024; i += 256) {
    int sx = i >> 9, k = (i >> 5) & 15, slot = i & 31;
    int q = slot >> 3, j = slot & 7;
    float v = 0.0f;
    if (q == 0 && j < 4) {
      int dx = j - sx;
      if (dx >= 0 && dx < 3) v = wp[k * 27 + 2 * 9 + 2 * 3 + dx];
    }
    wCS[sx][k][slot] = (_Float16)v;
  }
  if (tid < 16) bS[tid] = conv_b[(size_t)n * K_ + tid];

  // ---- xs fp16 staging: zero the 1-wide border ----
  for (int i = tid; i < 396; i += 256) {
    int c = i / 132, j = i - c * 132;
    int off;
    if (j < 34)       off = j;                       // top row
    else if (j < 68)  off = 33 * 34 + (j - 34);      // bottom row
    else if (j < 100) off = (j - 68 + 1) * 34;       // left col
    else              off = (j - 100 + 1) * 34 + 33; // right col
    xsh[c * XPITCH + off] = (_Float16)0.0f;
  }
  // interior: 768 float4 -> fp16
  const float4* xg = (const float4*)(x + (size_t)t * (C_ * P_ * P_));
  #pragma unroll
  for (int j = 0; j < 3; j++) {
    int i4 = tid + j * 256;
    float4 v = xg[i4];
    int f0 = i4 * 4;
    int c = f0 >> 10, rem = f0 & 1023, y = rem >> 5, xc = rem & 31;
    _Float16* dp = &xsh[c * XPITCH + (y + 1) * 34 + xc + 1];
    dp[0] = (_Float16)v.x; dp[1] = (_Float16)v.y;
    dp[2] = (_Float16)v.z; dp[3] = (_Float16)v.w;
  }
  __syncthreads();

  const int lane = tid & 63, wave = tid >> 6;
  const int lr = lane & 15, q = lane >> 4;
  const int ldy = lr >> 3, ldx = lr & 7;

  // fragment hoists (one-time)
  half8 aMain0 = *(const half8*)&wAS[0][lr][q * 8];
  half8 aMain1 = *(const half8*)&wAS[1][lr][q * 8];
  half8 aCorr0 = *(const half8*)&wCS[0][lr][q * 8];
  half8 aCorr1 = *(const half8*)&wCS[1][lr][q * 8];
  floatx4 cbias = *(const floatx4*)&bS[q * 4];

  // per-lane chunk-row base offsets (half elements)
  const int crL = q * 2, crH = crL + 1;
  const int cL = crL / 3, dyL = crL - cL * 3;
  const int cH = crH / 3, dyH = crH - cH * 3;
  const _Float16* chL = &xsh[cL * XPITCH + dyL * 34];
  const _Float16* chH = &xsh[cH * XPITCH + dyH * 34];
  const _Float16* chC = &xsh[2 * XPITCH + 2 * 34];

  #pragma unroll
  for (int i = 0; i < 4; i++) {
    const int qq = wave * 4 + i;
    const int py0 = (qq >> 1) * 2, px0 = (qq & 1) * 8;
    const int py = py0 + ldy, px = px0 + ldx;
    const int ebase = py * 68 + px * 2;   // (2py)*34 + 2px ; window starts raw col 2px-1
    const _Float16* pL = chL + ebase;
    const _Float16* pH = chH + ebase;
    const _Float16* pC = chC + ebase;

    floatx4 mx;
    #pragma unroll
    for (int sy = 0; sy < 2; sy++) {
      unsigned int uL0 = *(const unsigned int*)&pL[sy * 34];
      unsigned int uL1 = *(const unsigned int*)&pL[sy * 34 + 2];
      unsigned int uH0 = *(const unsigned int*)&pH[sy * 34];
      unsigned int uH1 = *(const unsigned int*)&pH[sy * 34 + 2];
      unsigned int uC0 = *(const unsigned int*)&pC[sy * 34];
      unsigned int uC1 = *(const unsigned int*)&pC[sy * 34 + 2];
      half8 bMain = __builtin_bit_cast(half8, (uint32x4){uL0, uL1, uH0, uH1});
      half8 bCorr = __builtin_bit_cast(half8, (uint32x4){uC0, uC1, uC0, uC1});
      floatx4 d0 = __builtin_amdgcn_mfma_f32_16x16x32_f16(aCorr0, bCorr, cbias, 0, 0, 0);
      d0 = __builtin_amdgcn_mfma_f32_16x16x32_f16(aMain0, bMain, d0, 0, 0, 0);
      floatx4 d1 = __builtin_amdgcn_mfma_f32_16x16x32_f16(aCorr1, bCorr, cbias, 0, 0, 0);
      d1 = __builtin_amdgcn_mfma_f32_16x16x32_f16(aMain1, bMain, d1, 0, 0, 0);
      floatx4 m;
      m[0] = fmaxf(d0[0], d1[0]); m[1] = fmaxf(d0[1], d1[1]);
      m[2] = fmaxf(d0[2], d1[2]); m[3] = fmaxf(d0[3], d1[3]);
      if (sy == 0) mx = m;
      else {
        mx[0] = fmaxf(mx[0], m[0]); mx[1] = fmaxf(mx[1], m[1]);
        mx[2] = fmaxf(mx[2], m[2]); mx[3] = fmaxf(mx[3], m[3]);
      }
    }
    _Float16* op = pooled + (size_t)t * FLAT_ + q * 1024 + py * 16 + px;
    op[0]   = (_Float16)fmaxf(mx[0], 0.0f);
    op[256] = (_Float16)fmaxf(mx[1], 0.0f);
    op[512] = (_Float16)fmaxf(mx[2], 0.0f);
    op[768] = (_Float16)fmaxf(mx[3], 0.0f);
  }
}

// ---------------------------------------------------------------------------
// K2: per-type linear via fp16 MFMA 16x16x32. Grid = 68 types x 16 f-chunks
// (K=256 each) = 1088 blocks, 256 threads. Wave: 32 rows x 64 outs (2x4
// frags). 4 K-steps of 64. B transposed into LDS via packed half2 writes.
// Writes DETERMINISTIC partials part[fc][t][64] fp32.
// ---------------------------------------------------------------------------
__global__ __launch_bounds__(256) void lin1_mfma_kernel(
    const _Float16* __restrict__ pooled, const float* __restrict__ lin1_w,
    float* __restrict__ part) {
  const int n   = blockIdx.x >> 4;
  const int fc  = blockIdx.x & 15;
  const int tid = threadIdx.x;
  const int wave = tid >> 6, lane = tid & 63;
  const int q = lane >> 4, lr = lane & 15;

  __shared__ __align__(16) _Float16 As[128 * 72];  // 128 rows x 64 k, pitch 72
  __shared__ __align__(16) _Float16 Bt[64 * 72];   // 64 outs x 64 k

  floatx4 acc[2][4];
  #pragma unroll
  for (int mt = 0; mt < 2; mt++)
    #pragma unroll
    for (int nt = 0; nt < 4; nt++)
      acc[mt][nt] = (floatx4){0.f, 0.f, 0.f, 0.f};

  const int f_base = fc * 256;
  for (int step = 0; step < 4; step++) {
    const int f0 = f_base + step * 64;

    // stage A: 128 rows x 64 fp16; 1024 16B-chunks, 4/thread
    #pragma unroll
    for (int j = 0; j < 4; j++) {
      int idx = tid + j * 256;
      int r = idx >> 3, ch = idx & 7;
      uint4 v = *(const uint4*)&pooled[(size_t)(r * N_ + n) * FLAT_ + f0 + ch * 8];
      *(uint4*)&As[r * 72 + ch * 8] = v;
    }
    // stage B: w slice [64 k][64 o]; cvt fp32->fp16 + transpose via half2 packs
    const float* wg = &lin1_w[(size_t)n * (FLAT_ * FD_) + (size_t)f0 * FD_];
    #pragma unroll
    for (int it = 0; it < 2; it++) {
      int p = tid + it * 256;            // 512 (k-pair, o-quad) units
      int o0 = (p & 15) * 4, k0 = (p >> 4) * 2;
      const float* wgk = wg + k0 * 64 + o0;
      float4 va = *(const float4*)wgk;
      float4 vb = *(const float4*)(wgk + 64);
      *(half2v*)&Bt[(o0 + 0) * 72 + k0] = (half2v){(_Float16)va.x, (_Float16)vb.x};
      *(half2v*)&Bt[(o0 + 1) * 72 + k0] = (half2v){(_Float16)va.y, (_Float16)vb.y};
      *(half2v*)&Bt[(o0 + 2) * 72 + k0] = (half2v){(_Float16)va.z, (_Float16)vb.z};
      *(half2v*)&Bt[(o0 + 3) * 72 + k0] = (half2v){(_Float16)va.w, (_Float16)vb.w};
    }
    __syncthreads();

    #pragma unroll
    for (int kh = 0; kh < 2; kh++) {
      half8 af[2], bf[4];
      #pragma unroll
      for (int mt = 0; mt < 2; mt++)
        af[mt] = *(const half8*)&As[(wave * 32 + mt * 16 + lr) * 72 + kh * 32 + q * 8];
      #pragma unroll
      for (int nt = 0; nt < 4; nt++)
        bf[nt] = *(const half8*)&Bt[(nt * 16 + lr) * 72 + kh * 32 + q * 8];
      #pragma unroll
      for (int mt = 0; mt < 2; mt++)
        #pragma unroll
        for (int nt = 0; nt < 4; nt++)
          acc[mt][nt] = __builtin_amdgcn_mfma_f32_16x16x32_f16(
              af[mt], bf[nt], acc[mt][nt], 0, 0, 0);
    }
    __syncthreads();
  }

  // store partials: D layout col=lane&15, row=quad*4+reg
  float* pb = part + (size_t)fc * T_ * FD_;
  #pragma unroll
  for (int mt = 0; mt < 2; mt++) {
    #pragma unroll
    for (int v = 0; v < 4; v++) {
      int r = wave * 32 + mt * 16 + q * 4 + v;
      size_t base = (size_t)(r * N_ + n) * FD_;
      #pragma unroll
      for (int nt = 0; nt < 4; nt++)
        pb[base + nt * 16 + lr] = acc[mt][nt][v];
    }
  }
}

// ---------------------------------------------------------------------------
// K3a: feats = relu(sum of 16 partials + lin1_b). Grid 544x256, float4/thread.
// ---------------------------------------------------------------------------
__global__ __launch_bounds__(256) void feats_kernel(
    const float* __restrict__ part, const float* __restrict__ lin1_b,
    float* __restrict__ feats) {
  int gid = blockIdx.x * 256 + threadIdx.x;      // T*64/4 = 139264 float4
  int t = gid >> 4, f4 = (gid & 15) * 4;
  int n = t % N_;
  float4 s = *(const float4*)&lin1_b[n * FD_ + f4];
  #pragma unroll
  for (int fc = 0; fc < FCH_; fc++) {
    float4 v = *(const float4*)&part[((size_t)fc * T_ + t) * FD_ + f4];
    s.x += v.x; s.y += v.y; s.z += v.z; s.w += v.w;
  }
  s.x = fmaxf(s.x, 0.f); s.y = fmaxf(s.y, 0.f);
  s.z = fmaxf(s.z, 0.f); s.w = fmaxf(s.w, 0.f);
  *(float4*)&feats[(size_t)t * FD_ + f4] = s;
}

// ---------------------------------------------------------------------------
// K3b: GCN aggregation, block = (graph, f-half of 32). 256 blocks x 256 thr.
// Edges + norms staged in LDS; scatter with LDS atomics (conflict-free banks).
// ---------------------------------------------------------------------------
__global__ __launch_bounds__(256) void gcn_agg_kernel(
    const float* __restrict__ feats, const int* __restrict__ edge_index,
    float* __restrict__ agg) {
  const int b  = blockIdx.x >> 1;
  const int fh = blockIdx.x & 1;        // f0 = fh*32
  const int tid = threadIdx.x;

  __shared__ float fS[N_ * 33], aS[N_ * 33];
  __shared__ int   esrcS[EG_], edstS[EG_];
  __shared__ float nrmS[EG_];
  __shared__ int   degS[N_];
  __shared__ float disS[N_];

  if (tid < N_) degS[tid] = 0;
  const int* srcp = edge_index;
  const int* dstp = edge_index + (B_ * EG_);
  const int e0 = b * EG_, nbase = b * N_;
  for (int e = tid; e < EG_; e += 256) {
    esrcS[e] = srcp[e0 + e] - nbase;
    edstS[e] = dstp[e0 + e] - nbase;
  }
  for (int idx = tid; idx < N_ * 32; idx += 256) {
    int i = idx >> 5, f = idx & 31;
    fS[i * 33 + f] = feats[(size_t)(b * N_ + i) * FD_ + fh * 32 + f];
  }
  __syncthreads();
  for (int e = tid; e < EG_; e += 256) atomicAdd(&degS[edstS[e]], 1);
  __syncthreads();
  if (tid < N_) disS[tid] = rsqrtf((float)(degS[tid] + 1));   // +1 self-loop
  __syncthreads();
  for (int e = tid; e < EG_; e += 256)
    nrmS[e] = disS[esrcS[e]] * disS[edstS[e]];
  for (int idx = tid; idx < N_ * 32; idx += 256) {
    int i = idx >> 5, f = idx & 31;
    float d = disS[i];
    aS[i * 33 + f] = d * d * fS[i * 33 + f];
  }
  __syncthreads();
  for (int idx = tid; idx < EG_ * 32; idx += 256) {
    int e = idx >> 5, f = idx & 31;
    atomicAdd(&aS[edstS[e] * 33 + f], nrmS[e] * fS[esrcS[e] * 33 + f]);
  }
  __syncthreads();
  for (int idx = tid; idx < N_ * 32; idx += 256) {
    int i = idx >> 5, f = idx & 31;
    agg[(size_t)(b * N_ + i) * FD_ + fh * 32 + f] = aS[i * 33 + f];
  }
}

// ---------------------------------------------------------------------------
// K3c: per-graph GEMM [68,64]@[64,128] + gcn_b + relu + mean-pool + MLP head.
// 128 blocks x 512 threads; w column hoisted to VGPRs (conflict-free reads).
// ---------------------------------------------------------------------------
__global__ __launch_bounds__(512) void gcn_head_kernel(
    const float* __restrict__ agg, const float* __restrict__ gcn_w,
    const float* __restrict__ gcn_b, const float* __restrict__ w1,
    const float* __restrict__ b1, const float* __restrict__ w2,
    const float* __restrict__ b2, float* __restrict__ out) {
  const int b = blockIdx.x;
  const int tid = threadIdx.x;

  __shared__ float aS[N_ * 68];      // [68][64] pitch 68
  __shared__ float wS[FD_ * GH_];    // 32 KB
  __shared__ float gP[4][GH_];
  __shared__ float z1S[64];

  for (int i4 = tid; i4 < N_ * 16; i4 += 512) {
    int i = i4 >> 4, qf = (i4 & 15) * 4;
    *(float4*)&aS[i * 68 + qf] = *(const float4*)&agg[(size_t)(b * N_ + i) * FD_ + qf];
  }
  #pragma unroll
  for (int j = 0; j < 4; j++)
    ((float4*)wS)[tid + j * 512] = ((const float4*)gcn_w)[tid + j * 512];
  __syncthreads();

  const int j = tid & 127, ig = tid >> 7;
  float wc[64];
  #pragma unroll
  for (int k = 0; k < 64; k++) wc[k] = wS[k * GH_ + j];
  const float bias = gcn_b[j];
  float gsum = 0.f;
  for (int i = ig; i < N_; i += 4) {
    float acc = bias;
    #pragma unroll
    for (int kq = 0; kq < 16; kq++) {
      float4 a = *(const float4*)&aS[i * 68 + kq * 4];   // broadcast
      acc += a.x * wc[kq * 4] + a.y * wc[kq * 4 + 1]
           + a.z * wc[kq * 4 + 2] + a.w * wc[kq * 4 + 3];
    }
    gsum += fmaxf(acc, 0.f);
  }
  gP[ig][j] = gsum;
  __syncthreads();
  if (tid < GH_)
    gP[0][tid] = (gP[0][tid] + gP[1][tid] + gP[2][tid] + gP[3][tid]) * (1.f / 68.f);
  __syncthreads();
  if (tid < 64) {
    float s = b1[tid];
    #pragma unroll 8
    for (int jj = 0; jj < GH_; jj++) s += gP[0][jj] * w1[jj * 64 + tid];
    z1S[tid] = fmaxf(s, 0.f);
  }
  __syncthreads();
  if (tid < 2) {
    float s = b2[tid];
    #pragma unroll 8
    for (int jj = 0; jj < 64; jj++) s += z1S[jj] * w2[jj * 2 + tid];
    out[b * 2 + tid] = s;
  }
}

// ---------------------------------------------------------------------------
extern "C" void kernel_launch(void* const* d_in, const int* in_sizes, int n_in,
                              void* d_out, int out_size, void* d_ws, size_t ws_size,
                              hipStream_t stream) {
  const float* x        = (const float*)d_in[0];
  const int*   edge_idx = (const int*)d_in[1];
  // d_in[2] = batch (layout known: t -> t/N), unused
  const float* conv_w   = (const float*)d_in[3];
  const float* conv_b   = (const float*)d_in[4];
  const float* lin1_w   = (const float*)d_in[5];
  const float* lin1_b   = (const float*)d_in[6];
  const float* gcn_w    = (const float*)d_in[7];
  const float* gcn_b    = (const float*)d_in[8];
  const float* mlp_w1   = (const float*)d_in[9];
  const float* mlp_b1   = (const float*)d_in[10];
  const float* mlp_w2   = (const float*)d_in[11];
  const float* mlp_b2   = (const float*)d_in[12];
  float* outp = (float*)d_out;

  char* wsb = (char*)d_ws;
  _Float16* pooled = (_Float16*)wsb;                               // 71.3 MB
  float* part  = (float*)(wsb + (size_t)T_ * FLAT_ * 2);           // 35.7 MB
  float* feats = part + (size_t)FCH_ * T_ * FD_;                   //  2.2 MB
  float* agg   = feats + (size_t)T_ * FD_;                         //  2.2 MB

  conv_pool_kernel<<<T_, 256, 0, stream>>>(x, conv_w, conv_b, pooled);
  lin1_mfma_kernel<<<N_ * FCH_, 256, 0, stream>>>(pooled, lin1_w, part);
  feats_kernel<<<544, 256, 0, stream>>>(part, lin1_b, feats);
  gcn_agg_kernel<<<B_ * 2, 256, 0, stream>>>(feats, edge_idx, agg);
  gcn_head_kernel<<<B_, 512, 0, stream>>>(agg, gcn_w, gcn_b,
                                          mlp_w1, mlp_b1, mlp_w2, mlp_b2, outp);
}

// Round 4
// 311.833 us; speedup vs baseline: 1.1403x; 1.0112x over previous
//
#include <hip/hip_runtime.h>
#include <hip/hip_fp16.h>

// Problem constants
#define B_   128
#define N_   68
#define C_   3
#define P_   32
#define K_   16
#define FD_  64
#define GH_  128
#define EG_  544          // 8*N
#define T_   8704         // B*N
#define FLAT_ 4096        // K*16*16
#define FCH_ 16           // f-chunks in lin1 (K-split of 256)

typedef __attribute__((ext_vector_type(8))) _Float16 half8;
typedef __attribute__((ext_vector_type(2))) _Float16 half2v;
typedef __attribute__((ext_vector_type(4))) float   floatx4;
typedef __attribute__((ext_vector_type(4))) unsigned int uint32x4;

// LDS image pitches chosen for bank-conflict-free MFMA B-fragment reads:
// row pitch 40 halves (20 dwords), channel pitch 1400 halves (700 dwords).
// Fragment base banks per q-group: (c*700 + dy*20)%32 = {0,8,16,24} ->
// each q spans 16 banks, wave64 = exactly 2 lanes/bank (free).
#define ROWP 40
#define CHP  1400

// ---------------------------------------------------------------------------
// K0: weight-fragment prep. Packs conv weights into MFMA A-fragments ONCE
// (was done per-block = 128x redundant + branchy VALU in the hot kernel).
// wfrag layout: [n][sx][type][k][slot32] halves; type 0 = main, 1 = corr.
//   main: slot = q*8 + r*4 + col ; cr = 2q+r -> c=cr/3, dy=cr%3 ; dx = col-sx
//   corr: q0 slots 0-3 = (c2,dy2) cols, rest zero.
// ---------------------------------------------------------------------------
__global__ __launch_bounds__(256) void wfrag_prep_kernel(
    const float* __restrict__ conv_w, _Float16* __restrict__ wfrag) {
  const int n = blockIdx.x;
  const int tid = threadIdx.x;
  const float* wp = conv_w + (size_t)n * (K_ * 27);
  _Float16* out = wfrag + (size_t)n * 2048;
  for (int i = tid; i < 2048; i += 256) {
    int sx   = (i >> 10) & 1;
    int type = (i >> 9) & 1;
    int k    = (i >> 5) & 15;
    int slot = i & 31;
    float v = 0.0f;
    if (type == 0) {
      int q = slot >> 3, r = (slot >> 2) & 1, col = slot & 3;
      int cr = q * 2 + r, c = cr / 3, dy = cr - c * 3, dx = col - sx;
      if (dx >= 0 && dx < 3) v = wp[k * 27 + c * 9 + dy * 3 + dx];
    } else {
      int q = slot >> 3, j = slot & 7;
      if (q == 0 && j < 4) {
        int dx = j - sx;
        if (dx >= 0 && dx < 3) v = wp[k * 27 + 24 + dx];  // c2,dy2 row
      }
    }
    out[i] = (_Float16)v;
  }
}

// ---------------------------------------------------------------------------
// K1: per-node conv3x3(SAME)+bias+relu+maxpool2x2 -> pooled[T][4096] fp16.
// MFMA formulation: D[16ch x 16 pooled-spatial] per quad, 4 sub-tiles
// (sy,sx in {0,1}^2) = the 4 pool partners, max'd in-lane. Fragments loaded
// from wfrag (coalesced 16B global, L2-hit), issued before the barrier.
// ---------------------------------------------------------------------------
__global__ __launch_bounds__(256) void conv_pool_kernel(
    const float* __restrict__ x, const _Float16* __restrict__ wfrag,
    const float* __restrict__ conv_b, _Float16* __restrict__ pooled) {
  const int t = blockIdx.x;
  const int n = t % N_;
  const int tid = threadIdx.x;

  __shared__ _Float16 xsh[3 * CHP];   // [c][34 rows x pitch 40] fp16

  const int lane = tid & 63;
  const int lr = lane & 15, q = lane >> 4;
  const int wave = tid >> 6;
  const int ldy = lr >> 3, ldx = lr & 7;

  // ---- issue x loads ----
  const float4* xg = (const float4*)(x + (size_t)t * (C_ * P_ * P_));
  float4 xv[3];
  #pragma unroll
  for (int j = 0; j < 3; j++) xv[j] = xg[tid + j * 256];

  // ---- fragment loads (independent of LDS; in flight during staging) ----
  const _Float16* wf = wfrag + (size_t)n * 2048 + lr * 32 + q * 8;
  half8 aMain0 = *(const half8*)&wf[0 * 512];   // sx0 main
  half8 aCorr0 = *(const half8*)&wf[1 * 512];   // sx0 corr
  half8 aMain1 = *(const half8*)&wf[2 * 512];   // sx1 main
  half8 aCorr1 = *(const half8*)&wf[3 * 512];   // sx1 corr
  floatx4 cbias = *(const floatx4*)&conv_b[(size_t)n * K_ + q * 4];

  // ---- zero the 1-wide border ----
  for (int i = tid; i < 396; i += 256) {
    int c = i / 132, j = i - c * 132;
    int off;
    if (j < 34)       off = j;                         // top row
    else if (j < 68)  off = 33 * ROWP + (j - 34);      // bottom row
    else if (j < 100) off = (j - 68 + 1) * ROWP;       // left col
    else              off = (j - 100 + 1) * ROWP + 33; // right col
    xsh[c * CHP + off] = (_Float16)0.0f;
  }
  // ---- interior: cvt fp32->fp16 ----
  #pragma unroll
  for (int j = 0; j < 3; j++) {
    int f0 = (tid + j * 256) * 4;
    int c = f0 >> 10, rem = f0 & 1023, y = rem >> 5, xc = rem & 31;
    _Float16* dp = &xsh[c * CHP + (y + 1) * ROWP + xc + 1];
    dp[0] = (_Float16)xv[j].x; dp[1] = (_Float16)xv[j].y;
    dp[2] = (_Float16)xv[j].z; dp[3] = (_Float16)xv[j].w;
  }
  __syncthreads();

  // per-lane chunk-row base pointers (chunk-rows cr = 2q, 2q+1)
  const int crL = q * 2, crH = crL + 1;
  const int cL = crL / 3, dyL = crL - cL * 3;
  const int cH = crH / 3, dyH = crH - cH * 3;
  const _Float16* chL = &xsh[cL * CHP + dyL * ROWP];
  const _Float16* chH = &xsh[cH * CHP + dyH * ROWP];
  const _Float16* chC = &xsh[2 * CHP + 2 * ROWP];

  #pragma unroll
  for (int i = 0; i < 4; i++) {
    const int qq = wave * 4 + i;
    const int py0 = (qq >> 1) * 2, px0 = (qq & 1) * 8;
    const int py = py0 + ldy, px = px0 + ldx;
    const int ebase = py * (2 * ROWP) + px * 2;
    const _Float16* pL = chL + ebase;
    const _Float16* pH = chH + ebase;
    const _Float16* pC = chC + ebase;

    floatx4 mx;
    #pragma unroll
    for (int sy = 0; sy < 2; sy++) {
      unsigned int uL0 = *(const unsigned int*)&pL[sy * ROWP];
      unsigned int uL1 = *(const unsigned int*)&pL[sy * ROWP + 2];
      unsigned int uH0 = *(const unsigned int*)&pH[sy * ROWP];
      unsigned int uH1 = *(const unsigned int*)&pH[sy * ROWP + 2];
      unsigned int uC0 = *(const unsigned int*)&pC[sy * ROWP];
      unsigned int uC1 = *(const unsigned int*)&pC[sy * ROWP + 2];
      half8 bMain = __builtin_bit_cast(half8, (uint32x4){uL0, uL1, uH0, uH1});
      half8 bCorr = __builtin_bit_cast(half8, (uint32x4){uC0, uC1, uC0, uC1});
      floatx4 d0 = __builtin_amdgcn_mfma_f32_16x16x32_f16(aCorr0, bCorr, cbias, 0, 0, 0);
      d0 = __builtin_amdgcn_mfma_f32_16x16x32_f16(aMain0, bMain, d0, 0, 0, 0);
      floatx4 d1 = __builtin_amdgcn_mfma_f32_16x16x32_f16(aCorr1, bCorr, cbias, 0, 0, 0);
      d1 = __builtin_amdgcn_mfma_f32_16x16x32_f16(aMain1, bMain, d1, 0, 0, 0);
      floatx4 m;
      m[0] = fmaxf(d0[0], d1[0]); m[1] = fmaxf(d0[1], d1[1]);
      m[2] = fmaxf(d0[2], d1[2]); m[3] = fmaxf(d0[3], d1[3]);
      if (sy == 0) mx = m;
      else {
        mx[0] = fmaxf(mx[0], m[0]); mx[1] = fmaxf(mx[1], m[1]);
        mx[2] = fmaxf(mx[2], m[2]); mx[3] = fmaxf(mx[3], m[3]);
      }
    }
    _Float16* op = pooled + (size_t)t * FLAT_ + q * 1024 + py * 16 + px;
    op[0]   = (_Float16)fmaxf(mx[0], 0.0f);
    op[256] = (_Float16)fmaxf(mx[1], 0.0f);
    op[512] = (_Float16)fmaxf(mx[2], 0.0f);
    op[768] = (_Float16)fmaxf(mx[3], 0.0f);
  }
}

// ---------------------------------------------------------------------------
// K2: per-type linear via fp16 MFMA 16x16x32. Grid = 68 types x 16 f-chunks
// (K=256 each) = 1088 blocks, 256 threads. Wave: 32 rows x 64 outs (2x4
// frags). 4 K-steps of 64. B transposed into LDS via packed half2 writes.
// Writes DETERMINISTIC partials part[fc][t][64] fp32.
// ---------------------------------------------------------------------------
__global__ __launch_bounds__(256) void lin1_mfma_kernel(
    const _Float16* __restrict__ pooled, const float* __restrict__ lin1_w,
    float* __restrict__ part) {
  const int n   = blockIdx.x >> 4;
  const int fc  = blockIdx.x & 15;
  const int tid = threadIdx.x;
  const int wave = tid >> 6, lane = tid & 63;
  const int q = lane >> 4, lr = lane & 15;

  __shared__ __align__(16) _Float16 As[128 * 72];  // 128 rows x 64 k, pitch 72
  __shared__ __align__(16) _Float16 Bt[64 * 72];   // 64 outs x 64 k

  floatx4 acc[2][4];
  #pragma unroll
  for (int mt = 0; mt < 2; mt++)
    #pragma unroll
    for (int nt = 0; nt < 4; nt++)
      acc[mt][nt] = (floatx4){0.f, 0.f, 0.f, 0.f};

  const int f_base = fc * 256;
  for (int step = 0; step < 4; step++) {
    const int f0 = f_base + step * 64;

    // stage A: 128 rows x 64 fp16; 1024 16B-chunks, 4/thread
    #pragma unroll
    for (int j = 0; j < 4; j++) {
      int idx = tid + j * 256;
      int r = idx >> 3, ch = idx & 7;
      uint4 v = *(const uint4*)&pooled[(size_t)(r * N_ + n) * FLAT_ + f0 + ch * 8];
      *(uint4*)&As[r * 72 + ch * 8] = v;
    }
    // stage B: w slice [64 k][64 o]; cvt fp32->fp16 + transpose via half2 packs
    const float* wg = &lin1_w[(size_t)n * (FLAT_ * FD_) + (size_t)f0 * FD_];
    #pragma unroll
    for (int it = 0; it < 2; it++) {
      int p = tid + it * 256;            // 512 (k-pair, o-quad) units
      int o0 = (p & 15) * 4, k0 = (p >> 4) * 2;
      const float* wgk = wg + k0 * 64 + o0;
      float4 va = *(const float4*)wgk;
      float4 vb = *(const float4*)(wgk + 64);
      *(half2v*)&Bt[(o0 + 0) * 72 + k0] = (half2v){(_Float16)va.x, (_Float16)vb.x};
      *(half2v*)&Bt[(o0 + 1) * 72 + k0] = (half2v){(_Float16)va.y, (_Float16)vb.y};
      *(half2v*)&Bt[(o0 + 2) * 72 + k0] = (half2v){(_Float16)va.z, (_Float16)vb.z};
      *(half2v*)&Bt[(o0 + 3) * 72 + k0] = (half2v){(_Float16)va.w, (_Float16)vb.w};
    }
    __syncthreads();

    #pragma unroll
    for (int kh = 0; kh < 2; kh++) {
      half8 af[2], bf[4];
      #pragma unroll
      for (int mt = 0; mt < 2; mt++)
        af[mt] = *(const half8*)&As[(wave * 32 + mt * 16 + lr) * 72 + kh * 32 + q * 8];
      #pragma unroll
      for (int nt = 0; nt < 4; nt++)
        bf[nt] = *(const half8*)&Bt[(nt * 16 + lr) * 72 + kh * 32 + q * 8];
      #pragma unroll
      for (int mt = 0; mt < 2; mt++)
        #pragma unroll
        for (int nt = 0; nt < 4; nt++)
          acc[mt][nt] = __builtin_amdgcn_mfma_f32_16x16x32_f16(
              af[mt], bf[nt], acc[mt][nt], 0, 0, 0);
    }
    __syncthreads();
  }

  // store partials: D layout col=lane&15, row=quad*4+reg
  float* pb = part + (size_t)fc * T_ * FD_;
  #pragma unroll
  for (int mt = 0; mt < 2; mt++) {
    #pragma unroll
    for (int v = 0; v < 4; v++) {
      int r = wave * 32 + mt * 16 + q * 4 + v;
      size_t base = (size_t)(r * N_ + n) * FD_;
      #pragma unroll
      for (int nt = 0; nt < 4; nt++)
        pb[base + nt * 16 + lr] = acc[mt][nt][v];
    }
  }
}

// ---------------------------------------------------------------------------
// K3a: feats = relu(sum of 16 partials + lin1_b). Grid 544x256, float4/thread.
// ---------------------------------------------------------------------------
__global__ __launch_bounds__(256) void feats_kernel(
    const float* __restrict__ part, const float* __restrict__ lin1_b,
    float* __restrict__ feats) {
  int gid = blockIdx.x * 256 + threadIdx.x;      // T*64/4 = 139264 float4
  int t = gid >> 4, f4 = (gid & 15) * 4;
  int n = t % N_;
  float4 s = *(const float4*)&lin1_b[n * FD_ + f4];
  #pragma unroll
  for (int fc = 0; fc < FCH_; fc++) {
    float4 v = *(const float4*)&part[((size_t)fc * T_ + t) * FD_ + f4];
    s.x += v.x; s.y += v.y; s.z += v.z; s.w += v.w;
  }
  s.x = fmaxf(s.x, 0.f); s.y = fmaxf(s.y, 0.f);
  s.z = fmaxf(s.z, 0.f); s.w = fmaxf(s.w, 0.f);
  *(float4*)&feats[(size_t)t * FD_ + f4] = s;
}

// ---------------------------------------------------------------------------
// K3b: GCN aggregation, block = (graph, f-half of 32). 256 blocks x 256 thr.
// Edges + norms staged in LDS; scatter with LDS atomics (conflict-free banks).
// ---------------------------------------------------------------------------
__global__ __launch_bounds__(256) void gcn_agg_kernel(
    const float* __restrict__ feats, const int* __restrict__ edge_index,
    float* __restrict__ agg) {
  const int b  = blockIdx.x >> 1;
  const int fh = blockIdx.x & 1;        // f0 = fh*32
  const int tid = threadIdx.x;

  __shared__ float fS[N_ * 33], aS[N_ * 33];
  __shared__ int   esrcS[EG_], edstS[EG_];
  __shared__ float nrmS[EG_];
  __shared__ int   degS[N_];
  __shared__ float disS[N_];

  if (tid < N_) degS[tid] = 0;
  const int* srcp = edge_index;
  const int* dstp = edge_index + (B_ * EG_);
  const int e0 = b * EG_, nbase = b * N_;
  for (int e = tid; e < EG_; e += 256) {
    esrcS[e] = srcp[e0 + e] - nbase;
    edstS[e] = dstp[e0 + e] - nbase;
  }
  for (int idx = tid; idx < N_ * 32; idx += 256) {
    int i = idx >> 5, f = idx & 31;
    fS[i * 33 + f] = feats[(size_t)(b * N_ + i) * FD_ + fh * 32 + f];
  }
  __syncthreads();
  for (int e = tid; e < EG_; e += 256) atomicAdd(&degS[edstS[e]], 1);
  __syncthreads();
  if (tid < N_) disS[tid] = rsqrtf((float)(degS[tid] + 1));   // +1 self-loop
  __syncthreads();
  for (int e = tid; e < EG_; e += 256)
    nrmS[e] = disS[esrcS[e]] * disS[edstS[e]];
  for (int idx = tid; idx < N_ * 32; idx += 256) {
    int i = idx >> 5, f = idx & 31;
    float d = disS[i];
    aS[i * 33 + f] = d * d * fS[i * 33 + f];
  }
  __syncthreads();
  for (int idx = tid; idx < EG_ * 32; idx += 256) {
    int e = idx >> 5, f = idx & 31;
    atomicAdd(&aS[edstS[e] * 33 + f], nrmS[e] * fS[esrcS[e] * 33 + f]);
  }
  __syncthreads();
  for (int idx = tid; idx < N_ * 32; idx += 256) {
    int i = idx >> 5, f = idx & 31;
    agg[(size_t)(b * N_ + i) * FD_ + fh * 32 + f] = aS[i * 33 + f];
  }
}

// ---------------------------------------------------------------------------
// K3c: per-graph GEMM [68,64]@[64,128] + gcn_b + relu + mean-pool + MLP head.
// 128 blocks x 512 threads; w column hoisted to VGPRs (conflict-free reads).
// ---------------------------------------------------------------------------
__global__ __launch_bounds__(512) void gcn_head_kernel(
    const float* __restrict__ agg, const float* __restrict__ gcn_w,
    const float* __restrict__ gcn_b, const float* __restrict__ w1,
    const float* __restrict__ b1, const float* __restrict__ w2,
    const float* __restrict__ b2, float* __restrict__ out) {
  const int b = blockIdx.x;
  const int tid = threadIdx.x;

  __shared__ float aS[N_ * 68];      // [68][64] pitch 68
  __shared__ float wS[FD_ * GH_];    // 32 KB
  __shared__ float gP[4][GH_];
  __shared__ float z1S[64];

  for (int i4 = tid; i4 < N_ * 16; i4 += 512) {
    int i = i4 >> 4, qf = (i4 & 15) * 4;
    *(float4*)&aS[i * 68 + qf] = *(const float4*)&agg[(size_t)(b * N_ + i) * FD_ + qf];
  }
  #pragma unroll
  for (int j = 0; j < 4; j++)
    ((float4*)wS)[tid + j * 512] = ((const float4*)gcn_w)[tid + j * 512];
  __syncthreads();

  const int j = tid & 127, ig = tid >> 7;
  float wc[64];
  #pragma unroll
  for (int k = 0; k < 64; k++) wc[k] = wS[k * GH_ + j];
  const float bias = gcn_b[j];
  float gsum = 0.f;
  for (int i = ig; i < N_; i += 4) {
    float acc = bias;
    #pragma unroll
    for (int kq = 0; kq < 16; kq++) {
      float4 a = *(const float4*)&aS[i * 68 + kq * 4];   // broadcast
      acc += a.x * wc[kq * 4] + a.y * wc[kq * 4 + 1]
           + a.z * wc[kq * 4 + 2] + a.w * wc[kq * 4 + 3];
    }
    gsum += fmaxf(acc, 0.f);
  }
  gP[ig][j] = gsum;
  __syncthreads();
  if (tid < GH_)
    gP[0][tid] = (gP[0][tid] + gP[1][tid] + gP[2][tid] + gP[3][tid]) * (1.f / 68.f);
  __syncthreads();
  if (tid < 64) {
    float s = b1[tid];
    #pragma unroll 8
    for (int jj = 0; jj < GH_; jj++) s += gP[0][jj] * w1[jj * 64 + tid];
    z1S[tid] = fmaxf(s, 0.f);
  }
  __syncthreads();
  if (tid < 2) {
    float s = b2[tid];
    #pragma unroll 8
    for (int jj = 0; jj < 64; jj++) s += z1S[jj] * w2[jj * 2 + tid];
    out[b * 2 + tid] = s;
  }
}

// ---------------------------------------------------------------------------
extern "C" void kernel_launch(void* const* d_in, const int* in_sizes, int n_in,
                              void* d_out, int out_size, void* d_ws, size_t ws_size,
                              hipStream_t stream) {
  const float* x        = (const float*)d_in[0];
  const int*   edge_idx = (const int*)d_in[1];
  // d_in[2] = batch (layout known: t -> t/N), unused
  const float* conv_w   = (const float*)d_in[3];
  const float* conv_b   = (const float*)d_in[4];
  const float* lin1_w   = (const float*)d_in[5];
  const float* lin1_b   = (const float*)d_in[6];
  const float* gcn_w    = (const float*)d_in[7];
  const float* gcn_b    = (const float*)d_in[8];
  const float* mlp_w1   = (const float*)d_in[9];
  const float* mlp_b1   = (const float*)d_in[10];
  const float* mlp_w2   = (const float*)d_in[11];
  const float* mlp_b2   = (const float*)d_in[12];
  float* outp = (float*)d_out;

  char* wsb = (char*)d_ws;
  _Float16* pooled = (_Float16*)wsb;                               // 71.3 MB
  float* part  = (float*)(wsb + (size_t)T_ * FLAT_ * 2);           // 35.7 MB
  float* feats = part + (size_t)FCH_ * T_ * FD_;                   //  2.2 MB
  float* agg   = feats + (size_t)T_ * FD_;                         //  2.2 MB
  _Float16* wfrag = (_Float16*)(agg + (size_t)T_ * FD_);           //  0.27 MB

  wfrag_prep_kernel<<<N_, 256, 0, stream>>>(conv_w, wfrag);
  conv_pool_kernel<<<T_, 256, 0, stream>>>(x, wfrag, conv_b, pooled);
  lin1_mfma_kernel<<<N_ * FCH_, 256, 0, stream>>>(pooled, lin1_w, part);
  feats_kernel<<<544, 256, 0, stream>>>(part, lin1_b, feats);
  gcn_agg_kernel<<<B_ * 2, 256, 0, stream>>>(feats, edge_idx, agg);
  gcn_head_kernel<<<B_, 512, 0, stream>>>(agg, gcn_w, gcn_b,
                                          mlp_w1, mlp_b1, mlp_w2, mlp_b2, outp);
}